// Round 7
// baseline (603.093 us; speedup 1.0000x reference)
//
#include <hip/hip_runtime.h>
#include <hip/hip_bf16.h>
#include <hip/hip_cooperative_groups.h>

namespace cg = cooperative_groups;

// REGATConv on MI355X — round 14. ONE cooperative dispatch (kill launch overhead).
//   Theory: ~110 µs of the 270 is inter-dispatch drain (6 serial graph nodes).
//   mega_k phases (grid.sync between): P1 fc_w convert + dst>>8 LDS hist ->
//   ghist[bin][nblk] | P2a per-block scan(256) + P2b block0 scan of totals |
//   P3 bucket-scatter via LDS cursors -> mid | P4 per-bucket counting-group ->
//   poffs, pk | P5 MFMA GEMM (64x256 tile) -> ftb, el, er | P6 agg (one wave
//   per dst, fused exp, single pass) -> out.
//   Grid 1024 = 4 blocks/CU (40KB LDS), __launch_bounds__(256,4) caps VGPR<=128
//   so co-residency is guaranteed; hipLaunchCooperativeKernel validates.
//   Fallback: round-13 6-dispatch path if cooperative launch is rejected.

#define NF 256
#define HD 256
#define NH 4

typedef __attribute__((ext_vector_type(8))) short short8;
typedef __attribute__((ext_vector_type(4))) float f32x4;

static __device__ __forceinline__ unsigned short f2bf(float f) {
  unsigned int u = __float_as_uint(f);
  u += 0x7FFFu + ((u >> 16) & 1u);   // RNE
  return (unsigned short)(u >> 16);
}
static __device__ __forceinline__ float bf2f(unsigned short s) {
  return __uint_as_float(((unsigned int)s) << 16);
}
static __device__ __forceinline__ unsigned pkbf(float a, float b) {
  __hip_bfloat162 h = __float22bfloat162_rn(make_float2(a, b));
  return *(unsigned*)&h;
}
static __device__ __forceinline__ float wcalc(float sum, float ew) {
  float x = sum * ew;
  x = (x >= 0.f) ? x : 0.2f * x;
  return __expf(x);
}

// ---------- shared device bodies ----------

// One GEMM tile: C[row0..row0+64)[0..256) = feat * fc_w^T, fused el/er epilogue.
static __device__ __forceinline__ void gemm_tile(
    const float* feat, const unsigned short* fcb, const float* attn_l,
    const float* attn_r, unsigned short* ftb, float* el, float* er,
    int n, int row0, int tid, short* aF, short* bF) {
  int lane = tid & 63, w = tid >> 6;
  f32x4 acc[4][4];
#pragma unroll
  for (int i = 0; i < 4; ++i)
#pragma unroll
    for (int j = 0; j < 4; ++j) acc[i][j] = (f32x4){0.f, 0.f, 0.f, 0.f};

  int ar = tid >> 2, ak = (tid & 3) << 4;
  int arow = row0 + ar; if (arow >= n) arow = n - 1;
  const float* ap = feat + (size_t)arow * NF + ak;
  int am = ar & 15, art = ar >> 4;
  int s0 = ak >> 5, q0 = (ak >> 3) & 3;
  int s1 = (ak + 8) >> 5, q1 = ((ak + 8) >> 3) & 3;
  short* aw0 = &aF[(((art * 2 + s0) * 64) + q0 * 16 + am) * 8];
  short* aw1 = &aF[(((art * 2 + s1) * 64) + q1 * 16 + am) * 8];

  const unsigned short* bp = fcb + (size_t)tid * NF;
  int bn = tid & 15, bcg = tid >> 4;

  for (int k0 = 0; k0 < NF; k0 += 64) {
    float4 f0 = *(const float4*)(ap + k0);
    float4 f1 = *(const float4*)(ap + k0 + 4);
    float4 f2 = *(const float4*)(ap + k0 + 8);
    float4 f3 = *(const float4*)(ap + k0 + 12);
    uint4 oa = make_uint4(pkbf(f0.x, f0.y), pkbf(f0.z, f0.w),
                          pkbf(f1.x, f1.y), pkbf(f1.z, f1.w));
    uint4 ob = make_uint4(pkbf(f2.x, f2.y), pkbf(f2.z, f2.w),
                          pkbf(f3.x, f3.y), pkbf(f3.z, f3.w));
    *(uint4*)aw0 = oa;
    *(uint4*)aw1 = ob;
#pragma unroll
    for (int o8 = 0; o8 < 8; ++o8) {
      short8 bv = *(const short8*)(bp + k0 + o8 * 8);
      int bs = o8 >> 2, bq = o8 & 3;
      *(short8*)&bF[(((bcg * 2 + bs) * 64) + bq * 16 + bn) * 8] = bv;
    }
    __syncthreads();
#pragma unroll
    for (int s = 0; s < 2; ++s) {
      short8 af[4], bfr[4];
#pragma unroll
      for (int rt = 0; rt < 4; ++rt)
        af[rt] = *(const short8*)&aF[(((rt * 2 + s) * 64) + lane) * 8];
#pragma unroll
      for (int ct = 0; ct < 4; ++ct)
        bfr[ct] = *(const short8*)&bF[((((w * 4 + ct) * 2 + s) * 64) + lane) * 8];
#pragma unroll
      for (int rt = 0; rt < 4; ++rt)
#pragma unroll
        for (int ct = 0; ct < 4; ++ct)
          acc[rt][ct] = __builtin_amdgcn_mfma_f32_16x16x32_bf16(
              af[rt], bfr[ct], acc[rt][ct], 0, 0, 0);
    }
    __syncthreads();
  }

  int ln = lane & 15, lq = lane >> 4;
  float al4[4], ar4[4];
#pragma unroll
  for (int ct = 0; ct < 4; ++ct) {
    al4[ct] = attn_l[w * 64 + ct * 16 + ln];
    ar4[ct] = attn_r[w * 64 + ct * 16 + ln];
  }
#pragma unroll
  for (int rt = 0; rt < 4; ++rt) {
#pragma unroll
    for (int r = 0; r < 4; ++r) {
      float pl = 0.f, pr = 0.f;
#pragma unroll
      for (int ct = 0; ct < 4; ++ct) {
        float v = acc[rt][ct][r];
        pl += v * al4[ct]; pr += v * ar4[ct];
      }
#pragma unroll
      for (int off = 1; off <= 8; off <<= 1) {
        pl += __shfl_xor(pl, off);
        pr += __shfl_xor(pr, off);
      }
      int row = row0 + rt * 16 + lq * 4 + r;
      if (row < n) {
        if (ln == 0) { el[row * NH + w] = pl; er[row * NH + w] = pr; }
        unsigned short* fr = ftb + (size_t)row * HD + w * 64 + ln;
#pragma unroll
        for (int ct = 0; ct < 4; ++ct) fr[ct * 16] = f2bf(acc[rt][ct][r]);
      }
    }
  }
}

// One node's aggregation by one wave (lane owns cols lane*4..+3, head=lane>>4).
static __device__ __forceinline__ void agg_node(
    const unsigned short* ftb, const int* pk, const float* el, const float* er,
    const float* ew_s, const int* poffs, float* out, int node, int lane) {
  int start = poffs[node];
  int deg = poffs[node + 1] - start;
  float o0 = 0.f, o1 = 0.f, o2 = 0.f, o3 = 0.f;
  if (deg > 0) {
    int hl = lane >> 4;
    float er_h = er[(size_t)node * NH + hl];
    const unsigned short* fb = ftb + (size_t)lane * 4;
    const float* elh = el + hl;
    const int* pg = pk + start;
    float ss = 0.f;
    int i = 0;
    for (; i + 8 <= deg; i += 8) {
      int4 pa = *(const int4*)(pg + i);
      int4 pb = *(const int4*)(pg + i + 4);
      int sA = pa.x & 0x1FFFF, tA = pa.x >> 17;
      int sB = pa.y & 0x1FFFF, tB = pa.y >> 17;
      int sC = pa.z & 0x1FFFF, tC = pa.z >> 17;
      int sD = pa.w & 0x1FFFF, tD = pa.w >> 17;
      int sE = pb.x & 0x1FFFF, tE = pb.x >> 17;
      int sF = pb.y & 0x1FFFF, tF = pb.y >> 17;
      int sG = pb.z & 0x1FFFF, tG = pb.z >> 17;
      int sH = pb.w & 0x1FFFF, tH = pb.w >> 17;
      float eA = elh[sA * NH], eB = elh[sB * NH], eC = elh[sC * NH], eD = elh[sD * NH];
      float eE = elh[sE * NH], eF = elh[sF * NH], eG = elh[sG * NH], eH = elh[sH * NH];
      ushort4 fA = *(const ushort4*)(fb + (size_t)sA * HD);
      ushort4 fB = *(const ushort4*)(fb + (size_t)sB * HD);
      ushort4 fC = *(const ushort4*)(fb + (size_t)sC * HD);
      ushort4 fD = *(const ushort4*)(fb + (size_t)sD * HD);
      ushort4 fE = *(const ushort4*)(fb + (size_t)sE * HD);
      ushort4 fF = *(const ushort4*)(fb + (size_t)sF * HD);
      ushort4 fG = *(const ushort4*)(fb + (size_t)sG * HD);
      ushort4 fH = *(const ushort4*)(fb + (size_t)sH * HD);
      float wA = wcalc(eA + er_h, ew_s[tA * NH + hl]);
      float wB = wcalc(eB + er_h, ew_s[tB * NH + hl]);
      float wC = wcalc(eC + er_h, ew_s[tC * NH + hl]);
      float wD = wcalc(eD + er_h, ew_s[tD * NH + hl]);
      float wE = wcalc(eE + er_h, ew_s[tE * NH + hl]);
      float wF = wcalc(eF + er_h, ew_s[tF * NH + hl]);
      float wG = wcalc(eG + er_h, ew_s[tG * NH + hl]);
      float wH = wcalc(eH + er_h, ew_s[tH * NH + hl]);
      ss += ((wA + wB) + (wC + wD)) + ((wE + wF) + (wG + wH));
      o0 = fmaf(wA, bf2f(fA.x), o0); o1 = fmaf(wA, bf2f(fA.y), o1);
      o2 = fmaf(wA, bf2f(fA.z), o2); o3 = fmaf(wA, bf2f(fA.w), o3);
      o0 = fmaf(wB, bf2f(fB.x), o0); o1 = fmaf(wB, bf2f(fB.y), o1);
      o2 = fmaf(wB, bf2f(fB.z), o2); o3 = fmaf(wB, bf2f(fB.w), o3);
      o0 = fmaf(wC, bf2f(fC.x), o0); o1 = fmaf(wC, bf2f(fC.y), o1);
      o2 = fmaf(wC, bf2f(fC.z), o2); o3 = fmaf(wC, bf2f(fC.w), o3);
      o0 = fmaf(wD, bf2f(fD.x), o0); o1 = fmaf(wD, bf2f(fD.y), o1);
      o2 = fmaf(wD, bf2f(fD.z), o2); o3 = fmaf(wD, bf2f(fD.w), o3);
      o0 = fmaf(wE, bf2f(fE.x), o0); o1 = fmaf(wE, bf2f(fE.y), o1);
      o2 = fmaf(wE, bf2f(fE.z), o2); o3 = fmaf(wE, bf2f(fE.w), o3);
      o0 = fmaf(wF, bf2f(fF.x), o0); o1 = fmaf(wF, bf2f(fF.y), o1);
      o2 = fmaf(wF, bf2f(fF.z), o2); o3 = fmaf(wF, bf2f(fF.w), o3);
      o0 = fmaf(wG, bf2f(fG.x), o0); o1 = fmaf(wG, bf2f(fG.y), o1);
      o2 = fmaf(wG, bf2f(fG.z), o2); o3 = fmaf(wG, bf2f(fG.w), o3);
      o0 = fmaf(wH, bf2f(fH.x), o0); o1 = fmaf(wH, bf2f(fH.y), o1);
      o2 = fmaf(wH, bf2f(fH.z), o2); o3 = fmaf(wH, bf2f(fH.w), o3);
    }
    for (; i < deg; ++i) {
      int pv = pg[i];
      int sA = pv & 0x1FFFF, tA = pv >> 17;
      float eA = elh[sA * NH];
      ushort4 fA = *(const ushort4*)(fb + (size_t)sA * HD);
      float wA = wcalc(eA + er_h, ew_s[tA * NH + hl]);
      ss += wA;
      o0 = fmaf(wA, bf2f(fA.x), o0); o1 = fmaf(wA, bf2f(fA.y), o1);
      o2 = fmaf(wA, bf2f(fA.z), o2); o3 = fmaf(wA, bf2f(fA.w), o3);
    }
    float rs = 1.0f / ss;
    o0 *= rs; o1 *= rs; o2 *= rs; o3 *= rs;
  }
  *(float4*)(out + (size_t)node * HD + lane * 4) = make_float4(o0, o1, o2, o3);
}

// ---------- cooperative mega-kernel (1 dispatch) ----------

__global__ __launch_bounds__(256, 4) void mega_k(
    const float* __restrict__ feat, const float* __restrict__ fc_w,
    const int* __restrict__ src, const int* __restrict__ dst,
    const int* __restrict__ efeats, const float* __restrict__ attn_l,
    const float* __restrict__ attn_r, const float* __restrict__ ewt,
    unsigned short* fcb, unsigned short* ftb, float* el, float* er,
    int* ghist, int* sg, int* btot, int* bbase, int* mid, int* pk,
    int* poffs, float* out, int n, int e) {
  cg::grid_group gg = cg::this_grid();
  __shared__ __align__(16) char smem[40960];
  int tid = threadIdx.x, blk = blockIdx.x;
  int nblk = gridDim.x;
  int lane = tid & 63, wid = tid >> 6;
  int epb = (e + nblk - 1) / nblk;
  int e0 = blk * epb, e1 = e0 + epb; if (e1 > e) e1 = e;

  // ---- P1: fc_w convert + dst>>8 histogram (ghist[bin][nblk])
  {
    int* bins = (int*)smem;
    bins[tid] = 0;
    int ci = blk * 256 + tid;
    if (ci < 16384) {
      float4 v = ((const float4*)fc_w)[ci];
      ((uint2*)fcb)[ci] = make_uint2(pkbf(v.x, v.y), pkbf(v.z, v.w));
    }
    __syncthreads();
    for (int i = e0 + tid; i < e1; i += 256)
      atomicAdd(&bins[dst[i] >> 8], 1);
    __syncthreads();
    ghist[tid * nblk + blk] = bins[tid];
  }
  gg.sync();

  // ---- P2a: block b exclusively scans ghist[b*256 .. b*256+256) -> sg; total -> btot[b]
  {
    int* wt = (int*)smem;
    int v = ghist[blk * 256 + tid];
    int inc = v;
#pragma unroll
    for (int off = 1; off < 64; off <<= 1) {
      int t = __shfl_up(inc, off);
      if (lane >= off) inc += t;
    }
    if (lane == 63) wt[wid] = inc;
    __syncthreads();
    int base = 0;
    if (wid > 0) base += wt[0];
    if (wid > 1) base += wt[1];
    if (wid > 2) base += wt[2];
    sg[blk * 256 + tid] = base + inc - v;
    if (tid == 255) btot[blk] = base + inc;
  }
  gg.sync();

  // ---- P2b: block 0 exclusively scans btot[nblk] -> bbase
  if (blk == 0) {
    int* wt = (int*)smem;
    int per = nblk >> 8;               // nblk is a multiple of 256; per in 1..4
    int vals[4]; int run = 0;
#pragma unroll
    for (int k = 0; k < 4; ++k) {
      vals[k] = (k < per) ? btot[tid * per + k] : 0;
      run += vals[k];
    }
    int inc = run;
#pragma unroll
    for (int off = 1; off < 64; off <<= 1) {
      int t = __shfl_up(inc, off);
      if (lane >= off) inc += t;
    }
    if (lane == 63) wt[wid] = inc;
    __syncthreads();
    int base = 0;
    if (wid > 0) base += wt[0];
    if (wid > 1) base += wt[1];
    if (wid > 2) base += wt[2];
    int eb = base + inc - run;
#pragma unroll
    for (int k = 0; k < 4; ++k)
      if (k < per) { bbase[tid * per + k] = eb; eb += vals[k]; }
  }
  gg.sync();

  // ---- P3: scatter edges into 256-node buckets (LDS cursors)
  {
    int* cur = (int*)smem;
    int j = tid * nblk + blk;
    cur[tid] = sg[j] + bbase[j >> 8];
    __syncthreads();
    for (int i = e0 + tid; i < e1; i += 256) {
      int d = dst[i];
      int pos = atomicAdd(&cur[d >> 8], 1);
      mid[pos] = src[i] | ((efeats[i] - 1) << 17) | ((d & 255) << 20);
    }
  }
  gg.sync();

  // ---- P4: per-bucket counting-group -> poffs + dst-grouped pk
  {
    int nbuck = (n + 255) >> 8;
    int* cnt = (int*)smem;
    int* cur = (int*)smem + 256;
    for (int b = blk; b < nbuck; b += nblk) {
      int j0 = b * nblk, j1 = (b + 1) * nblk;
      int bb0 = sg[j0] + bbase[j0 >> 8];
      int bb1 = sg[j1] + bbase[j1 >> 8];
      cnt[tid] = 0;
      __syncthreads();
      for (int i = bb0 + tid; i < bb1; i += 256)
        atomicAdd(&cnt[(mid[i] >> 20) & 255], 1);
      __syncthreads();
      if (tid < 64) {
        int carry = 0;
#pragma unroll
        for (int c = 0; c < 4; ++c) {
          int v = cnt[c * 64 + tid];
          int inc = v;
#pragma unroll
          for (int off = 1; off < 64; off <<= 1) {
            int t2 = __shfl_up(inc, off);
            if (tid >= off) inc += t2;
          }
          cur[c * 64 + tid] = inc - v + carry;
          carry += __shfl(inc, 63);
        }
      }
      __syncthreads();
      int node = b * 256 + tid;
      int gv = bb0 + cur[tid];
      if (node <= n) poffs[node] = gv;
      cur[tid] = gv;
      __syncthreads();
      for (int i = bb0 + tid; i < bb1; i += 256) {
        int v = mid[i];
        int pos = atomicAdd(&cur[(v >> 20) & 255], 1);
        pk[pos] = v & 0xFFFFF;
      }
      __syncthreads();
    }
  }
  __syncthreads();   // smem handoff to GEMM (no cross-block dep)

  // ---- P5: GEMM tiles (grid-stride)
  {
    short* aF = (short*)smem;             // 8 KB
    short* bF = (short*)(smem + 8192);    // 32 KB
    for (int t = blk; t * 64 < n; t += nblk)
      gemm_tile(feat, fcb, attn_l, attn_r, ftb, el, er, n, t * 64, tid, aF, bF);
  }
  gg.sync();

  // ---- P6: aggregation (one wave per node, grid-stride)
  {
    float* ew_s = (float*)smem;
    if (tid < 32) {
      float v = ewt[tid] * 100.0f;
      ew_s[tid] = (v >= 0.f) ? v : 0.01f * v;
    }
    __syncthreads();
    for (int nb = blk * 4; nb < n; nb += nblk * 4) {
      int node = nb + wid;
      if (node < n) agg_node(ftb, pk, el, er, ew_s, poffs, out, node, lane);
    }
  }
}

// ---------- fallback kernels (round-13 path, pb-parameterized) ----------

__global__ __launch_bounds__(256) void part_hist_k(
    const int* __restrict__ dst, const float* __restrict__ w,
    unsigned short* __restrict__ o, int* __restrict__ ghist, int e, int epb,
    int pb) {
  __shared__ int bins[256];
  int tid = threadIdx.x, blk = blockIdx.x;
  bins[tid] = 0;
  int ci = blk * 256 + tid;
  if (ci < 16384) {
    float4 v = ((const float4*)w)[ci];
    ((uint2*)o)[ci] = make_uint2(pkbf(v.x, v.y), pkbf(v.z, v.w));
  }
  __syncthreads();
  int e0 = blk * epb, e1 = e0 + epb; if (e1 > e) e1 = e;
  for (int i = e0 + tid; i < e1; i += 256)
    atomicAdd(&bins[dst[i] >> 8], 1);
  __syncthreads();
  ghist[tid * pb + blk] = bins[tid];
}

__global__ __launch_bounds__(1024) void scan2_k(const int* __restrict__ in,
                                                int* __restrict__ outp, int n) {
  __shared__ int wtot[16];
  __shared__ int wexcl[16];
  __shared__ int ctot;
  int tid = threadIdx.x, lane = tid & 63, wid = tid >> 6;
  int carry = 0;
  int nchunk = (n + 8191) >> 13;
  for (int c = 0; c < nchunk; ++c) {
    int base = (c << 13) + tid * 8;
    int v[8];
    if (base + 8 <= n) {
      int4 a = *(const int4*)(in + base);
      int4 b = *(const int4*)(in + base + 4);
      v[0] = a.x; v[1] = a.y; v[2] = a.z; v[3] = a.w;
      v[4] = b.x; v[5] = b.y; v[6] = b.z; v[7] = b.w;
    } else {
#pragma unroll
      for (int j = 0; j < 8; ++j) v[j] = (base + j < n) ? in[base + j] : 0;
    }
    int p[8]; int run = 0;
#pragma unroll
    for (int j = 0; j < 8; ++j) { run += v[j]; p[j] = run; }
    int incl = run;
#pragma unroll
    for (int off = 1; off < 64; off <<= 1) {
      int t = __shfl_up(incl, off);
      if (lane >= off) incl += t;
    }
    if (lane == 63) wtot[wid] = incl;
    __syncthreads();
    if (wid == 0 && lane < 16) {
      int wv = wtot[lane]; int wi = wv;
#pragma unroll
      for (int off = 1; off < 16; off <<= 1) {
        int t = __shfl_up(wi, off);
        if (lane >= off) wi += t;
      }
      wexcl[lane] = wi - wv;
      if (lane == 15) ctot = wi;
    }
    __syncthreads();
    int ebase = carry + wexcl[wid] + (incl - run);
#pragma unroll
    for (int j = 0; j < 8; ++j) {
      int i = base + j;
      if (i < n) outp[i] = ebase + p[j] - v[j];
    }
    carry += ctot;
    __syncthreads();
  }
  if (tid == 0) outp[n] = carry;
}

__global__ __launch_bounds__(256) void part_scatter_k(
    const int* __restrict__ src, const int* __restrict__ dst,
    const int* __restrict__ efeats, const int* __restrict__ sg,
    int* __restrict__ mid, int e, int epb, int pb) {
  __shared__ int cur[256];
  int tid = threadIdx.x, blk = blockIdx.x;
  cur[tid] = sg[tid * pb + blk];
  __syncthreads();
  int e0 = blk * epb, e1 = e0 + epb; if (e1 > e) e1 = e;
  for (int i = e0 + tid; i < e1; i += 256) {
    int d = dst[i];
    int pos = atomicAdd(&cur[d >> 8], 1);
    mid[pos] = src[i] | ((efeats[i] - 1) << 17) | ((d & 255) << 20);
  }
}

__global__ __launch_bounds__(256) void bucket_k(
    const int* __restrict__ mid, const int* __restrict__ sg,
    int* __restrict__ poffs, int* __restrict__ pk, int nN, int pb) {
  __shared__ int cnt[256];
  __shared__ int cur[256];
  int tid = threadIdx.x, b = blockIdx.x;
  int bb0 = sg[b * pb];
  int bb1 = sg[(b + 1) * pb];
  cnt[tid] = 0;
  __syncthreads();
  for (int i = bb0 + tid; i < bb1; i += 256)
    atomicAdd(&cnt[(mid[i] >> 20) & 255], 1);
  __syncthreads();
  if (tid < 64) {
    int carry = 0;
#pragma unroll
    for (int c = 0; c < 4; ++c) {
      int v = cnt[c * 64 + tid];
      int inc = v;
#pragma unroll
      for (int off = 1; off < 64; off <<= 1) {
        int t2 = __shfl_up(inc, off);
        if (tid >= off) inc += t2;
      }
      cur[c * 64 + tid] = inc - v + carry;
      carry += __shfl(inc, 63);
    }
  }
  __syncthreads();
  int node = b * 256 + tid;
  int g = bb0 + cur[tid];
  if (node <= nN) poffs[node] = g;
  cur[tid] = g;
  __syncthreads();
  for (int i = bb0 + tid; i < bb1; i += 256) {
    int v = mid[i];
    int pos = atomicAdd(&cur[(v >> 20) & 255], 1);
    pk[pos] = v & 0xFFFFF;
  }
}

__global__ __launch_bounds__(256) void gemm_k(
    const float* __restrict__ feat, const unsigned short* __restrict__ fcb,
    const float* __restrict__ attn_l, const float* __restrict__ attn_r,
    unsigned short* __restrict__ ftb, float* __restrict__ el,
    float* __restrict__ er, int n) {
  __shared__ short aF[4 * 2 * 64 * 8];
  __shared__ short bF[16 * 2 * 64 * 8];
  gemm_tile(feat, fcb, attn_l, attn_r, ftb, el, er, n,
            blockIdx.x * 64, threadIdx.x, aF, bF);
}

__global__ __launch_bounds__(256) void agg3_k(
    const unsigned short* __restrict__ ftb, const int* __restrict__ pk,
    const float* __restrict__ el, const float* __restrict__ er,
    const float* __restrict__ ewt, const int* __restrict__ offs,
    float* __restrict__ out, int n) {
  __shared__ float ew_s[32];
  if (threadIdx.x < 32) {
    float v = ewt[threadIdx.x] * 100.0f;
    ew_s[threadIdx.x] = (v >= 0.f) ? v : 0.01f * v;
  }
  __syncthreads();
  int node = blockIdx.x * 4 + (threadIdx.x >> 6);
  int lane = threadIdx.x & 63;
  if (node >= n) return;
  agg_node(ftb, pk, el, er, ew_s, offs, out, node, lane);
}

// ---------- launcher ----------

extern "C" void kernel_launch(void* const* d_in, const int* in_sizes, int n_in,
                              void* d_out, int out_size, void* d_ws, size_t ws_size,
                              hipStream_t stream) {
  const float* feat   = (const float*)d_in[0];
  const int*   src    = (const int*)d_in[1];
  const int*   dst    = (const int*)d_in[2];
  const int*   efeats = (const int*)d_in[3];
  const float* fc_w   = (const float*)d_in[4];
  const float* attn_l = (const float*)d_in[5];
  const float* attn_r = (const float*)d_in[6];
  const float* ewt    = (const float*)d_in[7];
  float* out = (float*)d_out;

  int N = in_sizes[0] / NF;   // 50000
  int E = in_sizes[1];        // 800000

  char* ws = (char*)d_ws;
  size_t off = 0;
  unsigned short* fcb = (unsigned short*)(ws + off); off += (size_t)NF * HD * 2;   // 128 KB
  unsigned short* ftb = (unsigned short*)(ws + off); off += (size_t)N * HD * 2;    // 25.6 MB
  float* el  = (float*)(ws + off);  off += (size_t)N * NH * 4;
  float* er  = (float*)(ws + off);  off += (size_t)N * NH * 4;
  int* poffs = (int*)(ws + off);    off += ((size_t)N + 16) * 4;
  int* ghist = (int*)(ws + off);    off += (size_t)1024 * 256 * 4;                 // 1 MB
  int* sg    = (int*)(ws + off);    off += ((size_t)1024 * 256 + 8) * 4;           // 1 MB
  int* btot  = (int*)(ws + off);    off += 1024 * 4;
  int* bbase = (int*)(ws + off);    off += 1024 * 4;
  int* mid   = (int*)(ws + off);    off += (size_t)E * 4;                           // 3.2 MB
  int* pk    = (int*)(ws + off);    off += (size_t)E * 4;                           // 3.2 MB

  // ---- try single cooperative dispatch
  int occ = 0;
  hipError_t oerr = hipOccupancyMaxActiveBlocksPerMultiprocessor(&occ, mega_k, 256, 0);
  bool coop_ok = (oerr == hipSuccess) && (occ >= 1);
  if (coop_ok) {
    if (occ > 4) occ = 4;
    int nblk = occ * 256;               // 256 CUs; multiple of 256 by construction
    void* args[] = {&feat, &fc_w, &src, &dst, &efeats, &attn_l, &attn_r, &ewt,
                    &fcb, &ftb, &el, &er, &ghist, &sg, &btot, &bbase,
                    &mid, &pk, &poffs, &out, &N, &E};
    hipError_t lerr = hipLaunchCooperativeKernel(mega_k, dim3(nblk), dim3(256),
                                                 args, 0, stream);
    if (lerr != hipSuccess) { (void)hipGetLastError(); coop_ok = false; }
  }

  // ---- fallback: round-13 six-dispatch path
  if (!coop_ok) {
    int pb = 256;
    int epb = (E + pb - 1) / pb;
    int nbuck = (N + 255) >> 8;
    part_hist_k<<<pb, 256, 0, stream>>>(dst, fc_w, fcb, ghist, E, epb, pb);
    scan2_k<<<1, 1024, 0, stream>>>(ghist, sg, pb * 256);
    part_scatter_k<<<pb, 256, 0, stream>>>(src, dst, efeats, sg, mid, E, epb, pb);
    bucket_k<<<nbuck, 256, 0, stream>>>(mid, sg, poffs, pk, N, pb);
    gemm_k<<<(N + 63) / 64, 256, 0, stream>>>(feat, fcb, attn_l, attn_r, ftb, el, er, N);
    agg3_k<<<(N + 3) / 4, 256, 0, stream>>>(ftb, pk, el, er, ewt, poffs, out, N);
  }
}

// Round 8
// 259.877 us; speedup vs baseline: 2.3207x; 2.3207x over previous
//
#include <hip/hip_runtime.h>
#include <hip/hip_bf16.h>

// REGATConv on MI355X — round 15. R13 sort + het-grid {GEMM ∥ scatter}.
//   ws: fcb bf16[256*256] | ftb bf16[N*256] | el[N*4] | er[N*4] | poffs[N+1]
//       | ghist int[256*PB] | sg int[256*PB+8] | mid int[E] | pk int[E]
//   PB = 242 partition blocks (so fused grid = 242 + 782 = 1024 = 4/CU exactly).
//   K1 part_hist (242 blocks): fc_w->bf16 convert + LDS 256-bin hist of dst>>8
//      -> ghist[bin][PB]. LDS atomics only.
//   K2 scan2 (1 block): exclusive scan of ghist flat (256*PB) -> sg
//   K3 fused: blocks [0,242) scatter edges into 256-node buckets via LDS
//      cursors (mid[pos] = src|et<<17|(dst&255)<<20); blocks [242,1024) MFMA
//      bf16 GEMM 64x256 tiles -> ftb, el, er. Roles are pipe-disjoint, no
//      global atomics; GEMM absorbs scatter time.
//   K4 bucket (196 blocks): per-bucket LDS counting-group -> poffs + pk
//   K5 agg3: one wave per dst; 8-unrolled gather; fused-exp single pass.

#define NF 256
#define HD 256
#define NH 4

typedef __attribute__((ext_vector_type(8))) short short8;
typedef __attribute__((ext_vector_type(4))) float f32x4;

static __device__ __forceinline__ unsigned short f2bf(float f) {
  unsigned int u = __float_as_uint(f);
  u += 0x7FFFu + ((u >> 16) & 1u);   // RNE
  return (unsigned short)(u >> 16);
}
static __device__ __forceinline__ float bf2f(unsigned short s) {
  return __uint_as_float(((unsigned int)s) << 16);
}
static __device__ __forceinline__ unsigned pkbf(float a, float b) {
  __hip_bfloat162 h = __float22bfloat162_rn(make_float2(a, b));
  return *(unsigned*)&h;
}
static __device__ __forceinline__ float wcalc(float sum, float ew) {
  float x = sum * ew;
  x = (x >= 0.f) ? x : 0.2f * x;
  return __expf(x);
}

// K1: per-block 256-bin LDS histogram of dst>>8 (+ fc_w convert, blocks 0..63)
__global__ __launch_bounds__(256) void part_hist_k(
    const int* __restrict__ dst, const float* __restrict__ w,
    unsigned short* __restrict__ o, int* __restrict__ ghist, int e, int epb,
    int pb) {
  __shared__ int bins[256];
  int tid = threadIdx.x, blk = blockIdx.x;
  bins[tid] = 0;
  int ci = blk * 256 + tid;
  if (ci < 16384) {
    float4 v = ((const float4*)w)[ci];
    ((uint2*)o)[ci] = make_uint2(pkbf(v.x, v.y), pkbf(v.z, v.w));
  }
  __syncthreads();
  int e0 = blk * epb, e1 = e0 + epb; if (e1 > e) e1 = e;
  for (int i = e0 + tid; i < e1; i += 256)
    atomicAdd(&bins[dst[i] >> 8], 1);
  __syncthreads();
  ghist[tid * pb + blk] = bins[tid];
}

// K2: single-block exclusive scan, 1024 thr x 8 -> chunk 8192
__global__ __launch_bounds__(1024) void scan2_k(const int* __restrict__ in,
                                                int* __restrict__ outp, int n) {
  __shared__ int wtot[16];
  __shared__ int wexcl[16];
  __shared__ int ctot;
  int tid = threadIdx.x, lane = tid & 63, wid = tid >> 6;
  int carry = 0;
  int nchunk = (n + 8191) >> 13;
  for (int c = 0; c < nchunk; ++c) {
    int base = (c << 13) + tid * 8;
    int v[8];
    if (base + 8 <= n) {
      int4 a = *(const int4*)(in + base);
      int4 b = *(const int4*)(in + base + 4);
      v[0] = a.x; v[1] = a.y; v[2] = a.z; v[3] = a.w;
      v[4] = b.x; v[5] = b.y; v[6] = b.z; v[7] = b.w;
    } else {
#pragma unroll
      for (int j = 0; j < 8; ++j) v[j] = (base + j < n) ? in[base + j] : 0;
    }
    int p[8]; int run = 0;
#pragma unroll
    for (int j = 0; j < 8; ++j) { run += v[j]; p[j] = run; }
    int incl = run;
#pragma unroll
    for (int off = 1; off < 64; off <<= 1) {
      int t = __shfl_up(incl, off);
      if (lane >= off) incl += t;
    }
    if (lane == 63) wtot[wid] = incl;
    __syncthreads();
    if (wid == 0 && lane < 16) {
      int wv = wtot[lane]; int wi = wv;
#pragma unroll
      for (int off = 1; off < 16; off <<= 1) {
        int t = __shfl_up(wi, off);
        if (lane >= off) wi += t;
      }
      wexcl[lane] = wi - wv;
      if (lane == 15) ctot = wi;
    }
    __syncthreads();
    int ebase = carry + wexcl[wid] + (incl - run);
#pragma unroll
    for (int j = 0; j < 8; ++j) {
      int i = base + j;
      if (i < n) outp[i] = ebase + p[j] - v[j];
    }
    carry += ctot;
    __syncthreads();
  }
  if (tid == 0) outp[n] = carry;
}

// K3: heterogeneous grid — scatter blocks [0,sb) FIRST, gemm blocks [sb,sb+gb).
// Scatter: LDS-cursor bucket scatter (same partition mapping as part_hist).
// GEMM: C[m][o] = sum_k feat[m][k]*fc_w[o][k]; 64x256 tile, wave=head, BK=64.
__global__ __launch_bounds__(256) void fused_k(
    const float* __restrict__ feat, const unsigned short* __restrict__ fcb,
    const float* __restrict__ attn_l, const float* __restrict__ attn_r,
    unsigned short* __restrict__ ftb, float* __restrict__ el,
    float* __restrict__ er, int n,
    const int* __restrict__ src, const int* __restrict__ dst,
    const int* __restrict__ efeats, const int* __restrict__ sg,
    int* __restrict__ mid, int e, int epb, int sb) {
  __shared__ short aF[4 * 2 * 64 * 8];    // [rt][s][lane][8]  8 KB
  __shared__ short bF[16 * 2 * 64 * 8];   // [cg][s][lane][8] 32 KB
  int tid = threadIdx.x;

  if (blockIdx.x < sb) {
    // ---- scatter role (overlaps GEMM blocks' compute; LDS atomics only)
    int* cur = (int*)aF;
    int blk = blockIdx.x;
    cur[tid] = sg[tid * sb + blk];
    __syncthreads();
    int e0 = blk * epb, e1 = e0 + epb; if (e1 > e) e1 = e;
    for (int i = e0 + tid; i < e1; i += 256) {
      int d = dst[i];
      int pos = atomicAdd(&cur[d >> 8], 1);
      mid[pos] = src[i] | ((efeats[i] - 1) << 17) | ((d & 255) << 20);
    }
    return;
  }

  int lane = tid & 63, w = tid >> 6;
  int row0 = (blockIdx.x - sb) * 64;

  f32x4 acc[4][4];
#pragma unroll
  for (int i = 0; i < 4; ++i)
#pragma unroll
    for (int j = 0; j < 4; ++j) acc[i][j] = (f32x4){0.f, 0.f, 0.f, 0.f};

  int ar = tid >> 2, ak = (tid & 3) << 4;
  int arow = row0 + ar; if (arow >= n) arow = n - 1;
  const float* ap = feat + (size_t)arow * NF + ak;
  int am = ar & 15, art = ar >> 4;
  int s0 = ak >> 5, q0 = (ak >> 3) & 3;
  int s1 = (ak + 8) >> 5, q1 = ((ak + 8) >> 3) & 3;
  short* aw0 = &aF[(((art * 2 + s0) * 64) + q0 * 16 + am) * 8];
  short* aw1 = &aF[(((art * 2 + s1) * 64) + q1 * 16 + am) * 8];

  const unsigned short* bp = fcb + (size_t)tid * NF;
  int bn = tid & 15, bcg = tid >> 4;

  for (int k0 = 0; k0 < NF; k0 += 64) {
    float4 f0 = *(const float4*)(ap + k0);
    float4 f1 = *(const float4*)(ap + k0 + 4);
    float4 f2 = *(const float4*)(ap + k0 + 8);
    float4 f3 = *(const float4*)(ap + k0 + 12);
    uint4 oa = make_uint4(pkbf(f0.x, f0.y), pkbf(f0.z, f0.w),
                          pkbf(f1.x, f1.y), pkbf(f1.z, f1.w));
    uint4 ob = make_uint4(pkbf(f2.x, f2.y), pkbf(f2.z, f2.w),
                          pkbf(f3.x, f3.y), pkbf(f3.z, f3.w));
    *(uint4*)aw0 = oa;
    *(uint4*)aw1 = ob;
#pragma unroll
    for (int o8 = 0; o8 < 8; ++o8) {
      short8 bv = *(const short8*)(bp + k0 + o8 * 8);
      int bs = o8 >> 2, bq = o8 & 3;
      *(short8*)&bF[(((bcg * 2 + bs) * 64) + bq * 16 + bn) * 8] = bv;
    }
    __syncthreads();
#pragma unroll
    for (int s = 0; s < 2; ++s) {
      short8 af[4], bfr[4];
#pragma unroll
      for (int rt = 0; rt < 4; ++rt)
        af[rt] = *(const short8*)&aF[(((rt * 2 + s) * 64) + lane) * 8];
#pragma unroll
      for (int ct = 0; ct < 4; ++ct)
        bfr[ct] = *(const short8*)&bF[((((w * 4 + ct) * 2 + s) * 64) + lane) * 8];
#pragma unroll
      for (int rt = 0; rt < 4; ++rt)
#pragma unroll
        for (int ct = 0; ct < 4; ++ct)
          acc[rt][ct] = __builtin_amdgcn_mfma_f32_16x16x32_bf16(
              af[rt], bfr[ct], acc[rt][ct], 0, 0, 0);
    }
    __syncthreads();
  }

  // epilogue: wave w == head w. C/D map: col = lane&15, row = (lane>>4)*4 + r.
  int ln = lane & 15, lq = lane >> 4;
  float al4[4], ar4[4];
#pragma unroll
  for (int ct = 0; ct < 4; ++ct) {
    al4[ct] = attn_l[w * 64 + ct * 16 + ln];
    ar4[ct] = attn_r[w * 64 + ct * 16 + ln];
  }
#pragma unroll
  for (int rt = 0; rt < 4; ++rt) {
#pragma unroll
    for (int r = 0; r < 4; ++r) {
      float pl = 0.f, pr = 0.f;
#pragma unroll
      for (int ct = 0; ct < 4; ++ct) {
        float v = acc[rt][ct][r];
        pl += v * al4[ct]; pr += v * ar4[ct];
      }
#pragma unroll
      for (int off = 1; off <= 8; off <<= 1) {
        pl += __shfl_xor(pl, off);
        pr += __shfl_xor(pr, off);
      }
      int row = row0 + rt * 16 + lq * 4 + r;
      if (row < n) {
        if (ln == 0) { el[row * NH + w] = pl; er[row * NH + w] = pr; }
        unsigned short* fr = ftb + (size_t)row * HD + w * 64 + ln;
#pragma unroll
        for (int ct = 0; ct < 4; ++ct) fr[ct * 16] = f2bf(acc[rt][ct][r]);
      }
    }
  }
}

// K4: per-bucket (256 nodes) LDS counting-group: poffs + dst-grouped pk
__global__ __launch_bounds__(256) void bucket_k(
    const int* __restrict__ mid, const int* __restrict__ sg,
    int* __restrict__ poffs, int* __restrict__ pk, int nN, int pb) {
  __shared__ int cnt[256];
  __shared__ int cur[256];
  int tid = threadIdx.x, b = blockIdx.x;
  int bb0 = sg[b * pb];
  int bb1 = sg[(b + 1) * pb];
  cnt[tid] = 0;
  __syncthreads();
  for (int i = bb0 + tid; i < bb1; i += 256)
    atomicAdd(&cnt[(mid[i] >> 20) & 255], 1);
  __syncthreads();
  if (tid < 64) {
    int carry = 0;
#pragma unroll
    for (int c = 0; c < 4; ++c) {
      int v = cnt[c * 64 + tid];
      int inc = v;
#pragma unroll
      for (int off = 1; off < 64; off <<= 1) {
        int t2 = __shfl_up(inc, off);
        if (tid >= off) inc += t2;
      }
      cur[c * 64 + tid] = inc - v + carry;
      carry += __shfl(inc, 63);
    }
  }
  __syncthreads();
  int node = b * 256 + tid;
  int g = bb0 + cur[tid];
  if (node <= nN) poffs[node] = g;
  cur[tid] = g;
  __syncthreads();
  for (int i = bb0 + tid; i < bb1; i += 256) {
    int v = mid[i];
    int pos = atomicAdd(&cur[(v >> 20) & 255], 1);
    pk[pos] = v & 0xFFFFF;
  }
}

// K5: one wave per dst node; lane owns output cols lane*4..lane*4+3 (head
// hl=lane>>4). Single pass: w=exp(leaky((el+er)*ew)) inline; scale by 1/ss.
__global__ __launch_bounds__(256) void agg3_k(
    const unsigned short* __restrict__ ftb, const int* __restrict__ pk,
    const float* __restrict__ el, const float* __restrict__ er,
    const float* __restrict__ ewt, const int* __restrict__ offs,
    float* __restrict__ out, int n) {
  __shared__ float ew_s[32];
  if (threadIdx.x < 32) {
    float v = ewt[threadIdx.x] * 100.0f;
    ew_s[threadIdx.x] = (v >= 0.f) ? v : 0.01f * v;
  }
  __syncthreads();
  int node = blockIdx.x * 4 + (threadIdx.x >> 6);
  int lane = threadIdx.x & 63;
  if (node >= n) return;
  int start = offs[node];
  int deg = offs[node + 1] - start;
  float o0 = 0.f, o1 = 0.f, o2 = 0.f, o3 = 0.f;
  if (deg > 0) {
    int hl = lane >> 4;
    float er_h = er[(size_t)node * NH + hl];
    const unsigned short* fb = ftb + (size_t)lane * 4;
    const float* elh = el + hl;
    const int* pg = pk + start;
    float ss = 0.f;
    int i = 0;
    for (; i + 8 <= deg; i += 8) {
      int4 pa = *(const int4*)(pg + i);
      int4 pb = *(const int4*)(pg + i + 4);
      int sA = pa.x & 0x1FFFF, tA = pa.x >> 17;
      int sB = pa.y & 0x1FFFF, tB = pa.y >> 17;
      int sC = pa.z & 0x1FFFF, tC = pa.z >> 17;
      int sD = pa.w & 0x1FFFF, tD = pa.w >> 17;
      int sE = pb.x & 0x1FFFF, tE = pb.x >> 17;
      int sF = pb.y & 0x1FFFF, tF = pb.y >> 17;
      int sG = pb.z & 0x1FFFF, tG = pb.z >> 17;
      int sH = pb.w & 0x1FFFF, tH = pb.w >> 17;
      float eA = elh[sA * NH], eB = elh[sB * NH], eC = elh[sC * NH], eD = elh[sD * NH];
      float eE = elh[sE * NH], eF = elh[sF * NH], eG = elh[sG * NH], eH = elh[sH * NH];
      ushort4 fA = *(const ushort4*)(fb + (size_t)sA * HD);
      ushort4 fB = *(const ushort4*)(fb + (size_t)sB * HD);
      ushort4 fC = *(const ushort4*)(fb + (size_t)sC * HD);
      ushort4 fD = *(const ushort4*)(fb + (size_t)sD * HD);
      ushort4 fE = *(const ushort4*)(fb + (size_t)sE * HD);
      ushort4 fF = *(const ushort4*)(fb + (size_t)sF * HD);
      ushort4 fG = *(const ushort4*)(fb + (size_t)sG * HD);
      ushort4 fH = *(const ushort4*)(fb + (size_t)sH * HD);
      float wA = wcalc(eA + er_h, ew_s[tA * NH + hl]);
      float wB = wcalc(eB + er_h, ew_s[tB * NH + hl]);
      float wC = wcalc(eC + er_h, ew_s[tC * NH + hl]);
      float wD = wcalc(eD + er_h, ew_s[tD * NH + hl]);
      float wE = wcalc(eE + er_h, ew_s[tE * NH + hl]);
      float wF = wcalc(eF + er_h, ew_s[tF * NH + hl]);
      float wG = wcalc(eG + er_h, ew_s[tG * NH + hl]);
      float wH = wcalc(eH + er_h, ew_s[tH * NH + hl]);
      ss += ((wA + wB) + (wC + wD)) + ((wE + wF) + (wG + wH));
      o0 = fmaf(wA, bf2f(fA.x), o0); o1 = fmaf(wA, bf2f(fA.y), o1);
      o2 = fmaf(wA, bf2f(fA.z), o2); o3 = fmaf(wA, bf2f(fA.w), o3);
      o0 = fmaf(wB, bf2f(fB.x), o0); o1 = fmaf(wB, bf2f(fB.y), o1);
      o2 = fmaf(wB, bf2f(fB.z), o2); o3 = fmaf(wB, bf2f(fB.w), o3);
      o0 = fmaf(wC, bf2f(fC.x), o0); o1 = fmaf(wC, bf2f(fC.y), o1);
      o2 = fmaf(wC, bf2f(fC.z), o2); o3 = fmaf(wC, bf2f(fC.w), o3);
      o0 = fmaf(wD, bf2f(fD.x), o0); o1 = fmaf(wD, bf2f(fD.y), o1);
      o2 = fmaf(wD, bf2f(fD.z), o2); o3 = fmaf(wD, bf2f(fD.w), o3);
      o0 = fmaf(wE, bf2f(fE.x), o0); o1 = fmaf(wE, bf2f(fE.y), o1);
      o2 = fmaf(wE, bf2f(fE.z), o2); o3 = fmaf(wE, bf2f(fE.w), o3);
      o0 = fmaf(wF, bf2f(fF.x), o0); o1 = fmaf(wF, bf2f(fF.y), o1);
      o2 = fmaf(wF, bf2f(fF.z), o2); o3 = fmaf(wF, bf2f(fF.w), o3);
      o0 = fmaf(wG, bf2f(fG.x), o0); o1 = fmaf(wG, bf2f(fG.y), o1);
      o2 = fmaf(wG, bf2f(fG.z), o2); o3 = fmaf(wG, bf2f(fG.w), o3);
      o0 = fmaf(wH, bf2f(fH.x), o0); o1 = fmaf(wH, bf2f(fH.y), o1);
      o2 = fmaf(wH, bf2f(fH.z), o2); o3 = fmaf(wH, bf2f(fH.w), o3);
    }
    for (; i < deg; ++i) {
      int pv = pg[i];
      int sA = pv & 0x1FFFF, tA = pv >> 17;
      float eA = elh[sA * NH];
      ushort4 fA = *(const ushort4*)(fb + (size_t)sA * HD);
      float wA = wcalc(eA + er_h, ew_s[tA * NH + hl]);
      ss += wA;
      o0 = fmaf(wA, bf2f(fA.x), o0); o1 = fmaf(wA, bf2f(fA.y), o1);
      o2 = fmaf(wA, bf2f(fA.z), o2); o3 = fmaf(wA, bf2f(fA.w), o3);
    }
    float rs = 1.0f / ss;
    o0 *= rs; o1 *= rs; o2 *= rs; o3 *= rs;
  }
  *(float4*)(out + (size_t)node * HD + lane * 4) = make_float4(o0, o1, o2, o3);
}

extern "C" void kernel_launch(void* const* d_in, const int* in_sizes, int n_in,
                              void* d_out, int out_size, void* d_ws, size_t ws_size,
                              hipStream_t stream) {
  const float* feat   = (const float*)d_in[0];
  const int*   src    = (const int*)d_in[1];
  const int*   dst    = (const int*)d_in[2];
  const int*   efeats = (const int*)d_in[3];
  const float* fc_w   = (const float*)d_in[4];
  const float* attn_l = (const float*)d_in[5];
  const float* attn_r = (const float*)d_in[6];
  const float* ewt    = (const float*)d_in[7];
  float* out = (float*)d_out;

  int N = in_sizes[0] / NF;   // 50000
  int E = in_sizes[1];        // 800000

  char* ws = (char*)d_ws;
  size_t off = 0;
  unsigned short* fcb = (unsigned short*)(ws + off); off += (size_t)NF * HD * 2;  // 128 KB
  unsigned short* ftb = (unsigned short*)(ws + off); off += (size_t)N * HD * 2;   // 25.6 MB
  float* el  = (float*)(ws + off);  off += (size_t)N * NH * 4;
  float* er  = (float*)(ws + off);  off += (size_t)N * NH * 4;
  int* poffs = (int*)(ws + off);    off += ((size_t)N + 16) * 4;
  int* ghist = (int*)(ws + off);    off += (size_t)256 * 256 * 4;                 // 256 KB
  int* sg    = (int*)(ws + off);    off += ((size_t)256 * 256 + 8) * 4;           // 256 KB
  int* mid   = (int*)(ws + off);    off += (size_t)E * 4;                          // 3.2 MB
  int* pk    = (int*)(ws + off);    off += (size_t)E * 4;                          // 3.2 MB

  int gb = (N + 63) / 64;            // 782 GEMM blocks
  int sb = 1024 - gb;                // 242 scatter/partition blocks
  int epb = (E + sb - 1) / sb;       // 3306 edges per partition block
  int nbuck = (N + 255) >> 8;        // 196 buckets (256 nodes each)

  part_hist_k<<<sb, 256, 0, stream>>>(dst, fc_w, fcb, ghist, E, epb, sb);
  scan2_k<<<1, 1024, 0, stream>>>(ghist, sg, 256 * sb);
  fused_k<<<sb + gb, 256, 0, stream>>>(feat, fcb, attn_l, attn_r, ftb, el, er, N,
                                       src, dst, efeats, sg, mid, E, epb, sb);
  bucket_k<<<nbuck, 256, 0, stream>>>(mid, sg, poffs, pk, N, sb);
  agg3_k<<<(N + 3) / 4, 256, 0, stream>>>(ftb, pk, el, er, ewt, poffs, out, N);
}